// Round 10
// baseline (376.804 us; speedup 1.0000x reference)
//
#include <hip/hip_runtime.h>
#include <stdint.h>

#define B_SZ 8192
#define D_SZ 1024
#define L_SZ 64
#define H_SZ 256

#define BM 256
#define BN 256
#define BK 64

typedef __attribute__((ext_vector_type(8))) __bf16 bf16x8;
typedef __attribute__((ext_vector_type(4))) float f32x4;

typedef __attribute__((address_space(1))) void as1_void;
typedef __attribute__((address_space(3))) void as3_void;

static __device__ __forceinline__ void gload_lds16(const void* g, void* l) {
    __builtin_amdgcn_global_load_lds((as1_void*)g, (as3_void*)l, 16, 0, 0);
}

static __device__ __forceinline__ unsigned short f2bf(float f) {
    uint32_t u = __builtin_bit_cast(uint32_t, f);
    u += 0x7fffu + ((u >> 16) & 1u);
    return (unsigned short)(u >> 16);
}

// ---------------- prep: x (fp32 [B][D]) -> bf16 ----------------
__global__ void cvt_x_kernel(const float* __restrict__ x, unsigned short* __restrict__ xb) {
    int i = blockIdx.x * blockDim.x + threadIdx.x;
    const float4 v = reinterpret_cast<const float4*>(x)[i];
    ushort4 o;
    o.x = f2bf(v.x); o.y = f2bf(v.y); o.z = f2bf(v.z); o.w = f2bf(v.w);
    reinterpret_cast<ushort4*>(xb)[i] = o;
}

// ------- prep: W1 (fp32 [L][D][H]) -> W1T bf16 [L][H][D] -------
__global__ void transpose_w1_kernel(const float* __restrict__ w1, unsigned short* __restrict__ w1t) {
    __shared__ float tile[64][65];
    int b = blockIdx.x;
    int l  = b >> 6;
    int dt = (b >> 2) & 15;
    int ht = b & 3;
    int tx = threadIdx.x & 63;
    int ty = threadIdx.x >> 6;
    const float* src = w1 + (size_t)l * (D_SZ * H_SZ);
    #pragma unroll
    for (int r = 0; r < 64; r += 4)
        tile[r + ty][tx] = src[(size_t)(dt * 64 + r + ty) * H_SZ + ht * 64 + tx];
    __syncthreads();
    unsigned short* dst = w1t + (size_t)l * (H_SZ * D_SZ);
    #pragma unroll
    for (int r = 0; r < 64; r += 4)
        dst[(size_t)(ht * 64 + r + ty) * D_SZ + dt * 64 + tx] = f2bf(tile[tx][r + ty]);
}

// ------ fused label-wise FFN GEMM, 256x256, 8-phase, B-frags pre-read ------
// grid: (B/256)*L = 2048 blocks, 512 threads (8 waves, 2M x 4N).
// R2 skeleton; new: next tile's B fragments ds_read one tile EARLY (2/phase)
// into a second reg set, so P0's 12-read burst becomes 6/6/6/6 + 4/6/8/6 and
// B-read latency is off the critical path. VMW(2)@P4 added per hazard ledger.

#define SBAR asm volatile("s_barrier" ::: "memory")
#define VMW(n) asm volatile("s_waitcnt vmcnt(" #n ")" ::: "memory")

#define DS_READ_A(c, quad) do { \
    _Pragma("unroll") for (int j = 0; j < 2; ++j) { \
        const int rowh = ((quad)*2 + j)*16 + rl; \
        _Pragma("unroll") for (int ks = 0; ks < 2; ++ks) { \
            const int slot = (ks*4 + g) ^ (rowh & 7); \
            af[ks][j] = *reinterpret_cast<const bf16x8*>( \
                reinterpret_cast<const char*>(&ldsA[c][wr][0]) + rowh*128 + slot*16); \
        } } } while(0)

// 2 B-frag reads: j=0: ks0 nf{0,1}; j=1: ks0 nf{2,3}; j=2: ks1 nf{0,1}; j=3: ks1 nf{2,3}
#define BN2(c, dst, jj) do { \
    const int ks = (jj) >> 1; \
    _Pragma("unroll") for (int p = 0; p < 2; ++p) { \
        const int nf = ((jj) & 1) * 2 + p; \
        const int rowb = wc*64 + nf*16 + rl; \
        const int bh = rowb >> 7; \
        const int rowh = rowb & 127; \
        const int slot = (ks*4 + g) ^ (rowh & 7); \
        dst[ks][nf] = *reinterpret_cast<const bf16x8*>( \
            reinterpret_cast<const char*>(&ldsB[c][bh][0]) + rowh*128 + slot*16); \
    } } while(0)

#define MFMA_QUAD(quad, bfX) do { \
    __builtin_amdgcn_s_setprio(1); \
    _Pragma("unroll") for (int ks = 0; ks < 2; ++ks) \
    _Pragma("unroll") for (int j = 0; j < 2; ++j) \
    _Pragma("unroll") for (int nf = 0; nf < 4; ++nf) \
        acc[(quad)*2 + j][nf] = __builtin_amdgcn_mfma_f32_16x16x32_bf16( \
            af[ks][j], bfX[ks][nf], acc[(quad)*2 + j][nf], 0, 0, 0); \
    __builtin_amdgcn_s_setprio(0); } while(0)

#define STAGE_A(t, h) do { \
    gload_lds16(aSrc[h][0] + (size_t)(t)*BK, &ldsA[(t)&1][h][(wid*64)*8]); \
    gload_lds16(aSrc[h][1] + (size_t)(t)*BK, &ldsA[(t)&1][h][(512 + wid*64)*8]); } while(0)

#define STAGE_B(t, h) do { \
    gload_lds16(bSrc[h][0] + (size_t)(t)*BK, &ldsB[(t)&1][h][(wid*64)*8]); \
    gload_lds16(bSrc[h][1] + (size_t)(t)*BK, &ldsB[(t)&1][h][(512 + wid*64)*8]); } while(0)

__global__ __launch_bounds__(512, 2) void ffn_gemm_kernel(
    const unsigned short* __restrict__ xb,    // bf16 [B][D]
    const unsigned short* __restrict__ w1t,   // bf16 [L][H][D]
    const float* __restrict__ b1,             // [L][H]
    const float* __restrict__ w2,             // [L][H]
    const float* __restrict__ b2,             // [L]
    float* __restrict__ out)                  // f32 [B][L]
{
    // [dbuf][half][128 rows * 64 K] bf16 = 64 KiB each for A and B
    __shared__ unsigned short ldsA[2][2][128 * 64];
    __shared__ unsigned short ldsB[2][2][128 * 64];
    __shared__ float partRed[256][4];

    // bijective XCD swizzle (2048 % 8 == 0): 32 consecutive wgs share one
    // label -> W1T_l panel (512 KB) hot in that XCD's L2; sequential blocks
    // on a CU keep the same m0 -> A panel L2-hot across blocks.
    const int bid = blockIdx.x;
    const int wg  = ((bid & 7) << 8) + (bid >> 3);
    const int l   = wg >> 5;
    const int m0  = (wg & 31) * BM;

    const int tid  = threadIdx.x;
    const int wid  = tid >> 6;
    const int lane = tid & 63;
    const int wr   = wid >> 2;   // 0..1
    const int wc   = wid & 3;    // 0..3
    const int g    = lane >> 4;  // 0..3
    const int rl   = lane & 15;

    // Pre-swizzled global sources (rule #21), exactly R2's
    const unsigned short* aSrc[2][2];
    const unsigned short* bSrc[2][2];
    #pragma unroll
    for (int h = 0; h < 2; ++h)
        #pragma unroll
        for (int c2 = 0; c2 < 2; ++c2) {
            const int q  = c2 * 512 + tid;
            const int r  = q >> 3;
            const int kg = (q & 7) ^ (r & 7);
            aSrc[h][c2] = xb  + (size_t)(m0 + h * 128 + r) * D_SZ + kg * 8;
            bSrc[h][c2] = w1t + ((size_t)l * H_SZ + h * 128 + r) * D_SZ + kg * 8;
        }

    // epilogue constants hoisted
    float b1v[4], w2v[4];
    #pragma unroll
    for (int nf = 0; nf < 4; ++nf) {
        const int col = wc * 64 + nf * 16 + rl;
        b1v[nf] = b1[l * H_SZ + col];
        w2v[nf] = w2[l * H_SZ + col];
    }
    const float b2v = b2[l];

    f32x4 acc[8][4];
    #pragma unroll
    for (int m = 0; m < 8; ++m)
        #pragma unroll
        for (int n = 0; n < 4; ++n) {
            acc[m][n][0] = 0.f; acc[m][n][1] = 0.f;
            acc[m][n][2] = 0.f; acc[m][n][3] = 0.f;
        }

    bf16x8 af[2][2];
    bf16x8 bfE[2][4], bfO[2][4];   // current even/odd tile B frags

    // Prologue: B(0), A(0), B(1); full drain once, then pre-read B(0) frags.
    STAGE_B(0, 0); STAGE_B(0, 1);
    STAGE_A(0, 0); STAGE_A(0, 1);
    STAGE_B(1, 0); STAGE_B(1, 1);
    VMW(0);
    SBAR;
    BN2(0, bfE, 0); BN2(0, bfE, 1); BN2(0, bfE, 2); BN2(0, bfE, 3);

    // Main loop. Ledger per iteration i (tiles e=2i buf0, o=2i+1 buf1):
    //  P3 VMW(4): outstanding A(t1)4+B(t2)4 -> retires A(t1), leaves B(t2).
    //  P4 VMW(2): outstanding B(t2)4+A(t2,0)2 -> retires B(t2) (pre-reads of
    //             B(t2) start P5). P7 VMW(4): A(t2)4+B(t3)4 -> retires A(t2).
    //  bfO written P0-P3 (read P4-P7); bfE written P5-P7 (read next P0-P3).
    #pragma unroll 1
    for (int i = 0; i < 7; ++i) {
        const int t1 = 2 * i + 1, t2 = 2 * i + 2, t3 = 2 * i + 3;
        // even tile (buf0, bfE) — pre-read B(t1) -> bfO, 2 reads/phase
        DS_READ_A(0, 0); BN2(1, bfO, 0); STAGE_A(t1, 0); SBAR; MFMA_QUAD(0, bfE); SBAR;
        DS_READ_A(0, 1); BN2(1, bfO, 1); STAGE_A(t1, 1); SBAR; MFMA_QUAD(1, bfE); SBAR;
        DS_READ_A(0, 2); BN2(1, bfO, 2); STAGE_B(t2, 0); SBAR; MFMA_QUAD(2, bfE); SBAR;
        DS_READ_A(0, 3); BN2(1, bfO, 3); STAGE_B(t2, 1); SBAR; MFMA_QUAD(3, bfE); VMW(4); SBAR;
        // odd tile (buf1, bfO) — pre-read B(t2) -> bfE after VMW(2)
        DS_READ_A(1, 0);                                 STAGE_A(t2, 0); SBAR; MFMA_QUAD(0, bfO); VMW(2); SBAR;
        DS_READ_A(1, 1); BN2(0, bfE, 0);                 STAGE_A(t2, 1); SBAR; MFMA_QUAD(1, bfO); SBAR;
        DS_READ_A(1, 2); BN2(0, bfE, 1); BN2(0, bfE, 2); STAGE_B(t3, 0); SBAR; MFMA_QUAD(2, bfO); SBAR;
        DS_READ_A(1, 3); BN2(0, bfE, 3);                 STAGE_B(t3, 1); SBAR; MFMA_QUAD(3, bfO); VMW(4); SBAR;
    }
    // Tail: tiles 14 (buf0, bfE pre-read during i=6) and 15 (buf1).
    VMW(0);   // retire B(15) (only outstanding) before its pre-reads
    DS_READ_A(0, 0);                                 STAGE_A(15, 0); SBAR; MFMA_QUAD(0, bfE); SBAR;
    DS_READ_A(0, 1); BN2(1, bfO, 0); BN2(1, bfO, 1); STAGE_A(15, 1); SBAR; MFMA_QUAD(1, bfE); SBAR;
    DS_READ_A(0, 2); BN2(1, bfO, 2); BN2(1, bfO, 3);                 SBAR; MFMA_QUAD(2, bfE); SBAR;
    DS_READ_A(0, 3);                                                 SBAR; MFMA_QUAD(3, bfE); VMW(0); SBAR;
    DS_READ_A(1, 0); SBAR; MFMA_QUAD(0, bfO); SBAR;
    DS_READ_A(1, 1); SBAR; MFMA_QUAD(1, bfO); SBAR;
    DS_READ_A(1, 2); SBAR; MFMA_QUAD(2, bfO); SBAR;
    DS_READ_A(1, 3); SBAR; MFMA_QUAD(3, bfO);

    // ---- fused epilogue: out[row, l] = sum_h relu(C + b1)*w2 + b2 ----
    #pragma unroll
    for (int mf = 0; mf < 8; ++mf) {
        #pragma unroll
        for (int r = 0; r < 4; ++r) {
            float p = 0.f;
            #pragma unroll
            for (int nf = 0; nf < 4; ++nf) {
                float v = acc[mf][nf][r] + b1v[nf];
                v = fmaxf(v, 0.f);
                p += v * w2v[nf];
            }
            p += __shfl_xor(p, 1);
            p += __shfl_xor(p, 2);
            p += __shfl_xor(p, 4);
            p += __shfl_xor(p, 8);
            if (rl == 0)
                partRed[wr * 128 + mf * 16 + g * 4 + r][wc] = p;
        }
    }
    __syncthreads();
    if (tid < BM) {
        float s = b2v;
        #pragma unroll
        for (int w = 0; w < 4; ++w) s += partRed[tid][w];
        out[(size_t)(m0 + tid) * L_SZ + l] = s;
    }
}

extern "C" void kernel_launch(void* const* d_in, const int* in_sizes, int n_in,
                              void* d_out, int out_size, void* d_ws, size_t ws_size,
                              hipStream_t stream) {
    const float* x  = (const float*)d_in[0];
    const float* W1 = (const float*)d_in[1];
    const float* b1 = (const float*)d_in[2];
    const float* W2 = (const float*)d_in[3];
    const float* b2 = (const float*)d_in[4];
    float* out = (float*)d_out;

    unsigned short* xb  = (unsigned short*)d_ws;                 // 16 MB
    unsigned short* w1t = xb + (size_t)B_SZ * D_SZ;              // 32 MB

    cvt_x_kernel<<<(B_SZ * D_SZ / 4) / 256, 256, 0, stream>>>(x, xb);
    transpose_w1_kernel<<<L_SZ * 16 * 4, 256, 0, stream>>>(W1, w1t);
    ffn_gemm_kernel<<<(B_SZ / BM) * L_SZ, 512, 0, stream>>>(xb, w1t, b1, W2, b2, out);
}